// Round 1
// baseline (150.096 us; speedup 1.0000x reference)
//
#include <hip/hip_runtime.h>

// LoFTR2Tensor: jagged -> padded dense scatter.
// With sorted batch_indexes and per-batch counts == max_points this is a
// pure reshape/copy; we still handle the general sorted-jagged case via a
// starts[] table (binary search), but never touch the 67MB batch_indexes
// array in the hot kernel.

#define MAX_B 1024

__global__ void loftr_compute_starts(const int* __restrict__ batch_indexes, int n,
                                     const int* __restrict__ num_batches_p,
                                     int* __restrict__ starts) {
    int B = *num_batches_p;
    int b = blockIdx.x * blockDim.x + threadIdx.x;
    if (b >= B) return;
    // lower_bound: first i with batch_indexes[i] >= b  (batch_indexes sorted)
    int lo = 0, hi = n;
    while (lo < hi) {
        int mid = (int)(((unsigned)lo + (unsigned)hi) >> 1);
        if (batch_indexes[mid] < b) lo = mid + 1; else hi = mid;
    }
    starts[b] = lo;
}

__global__ void loftr_scatter(const float* __restrict__ kp0,
                              const float* __restrict__ kp1,
                              const float* __restrict__ conf,
                              const int* __restrict__ starts_g,
                              const int* __restrict__ num_batches_p,
                              const int* __restrict__ max_points_p,
                              float* __restrict__ out,
                              int n, long long M /* = num_batches*max_points */) {
    __shared__ int s_starts[MAX_B];
    const int B = *num_batches_p;
    const int L = *max_points_p;
    for (int t = threadIdx.x; t < B; t += blockDim.x) s_starts[t] = starts_g[t];
    __syncthreads();

    float* __restrict__ src = out;            // (B, L, 2)
    float* __restrict__ tgt = out + 2 * M;    // (B, L, 2)
    float* __restrict__ sco = out + 4 * M;    // (B, L)

    const long long nq = ((long long)n + 3) >> 2;
    const long long tstride = (long long)gridDim.x * blockDim.x;
    for (long long q = (long long)blockIdx.x * blockDim.x + threadIdx.x; q < nq; q += tstride) {
        const long long i0 = q << 2;
        const int rem = (int)((n - i0) < 4 ? (n - i0) : 4);

        // find batch of i0: largest b with s_starts[b] <= i0
        int l = 1, h = B;
        while (l < h) {
            int m = (l + h) >> 1;
            if ((long long)s_starts[m] <= i0) l = m + 1; else h = m;
        }
        const int b0 = l - 1;
        const long long st = s_starts[b0];
        const long long next = (b0 + 1 < B) ? (long long)s_starts[b0 + 1] : (long long)n;
        const long long pos0 = i0 - st;
        const long long base = (long long)b0 * L + pos0;

        const bool fast = (rem == 4) && (i0 + 3 < next) && (pos0 + 3 < (long long)L) &&
                          ((base & 3LL) == 0LL);
        if (fast) {
            // 4 points, all in batch b0, contiguous + 16B-aligned in and out.
            const float4 a0 = *reinterpret_cast<const float4*>(kp0 + 2 * i0);
            const float4 a1 = *reinterpret_cast<const float4*>(kp0 + 2 * i0 + 4);
            const float4 b0v = *reinterpret_cast<const float4*>(kp1 + 2 * i0);
            const float4 b1v = *reinterpret_cast<const float4*>(kp1 + 2 * i0 + 4);
            const float4 c0 = *reinterpret_cast<const float4*>(conf + i0);
            *reinterpret_cast<float4*>(src + 2 * base)     = a0;
            *reinterpret_cast<float4*>(src + 2 * base + 4) = a1;
            *reinterpret_cast<float4*>(tgt + 2 * base)     = b0v;
            *reinterpret_cast<float4*>(tgt + 2 * base + 4) = b1v;
            *reinterpret_cast<float4*>(sco + base)         = c0;
        } else {
            for (int j = 0; j < rem; ++j) {
                const long long i = i0 + j;
                int ll = 1, hh = B;
                while (ll < hh) {
                    int m = (ll + hh) >> 1;
                    if ((long long)s_starts[m] <= i) ll = m + 1; else hh = m;
                }
                const int b = ll - 1;
                const long long pos = i - (long long)s_starts[b];
                if (pos < (long long)L) {   // mode="drop"
                    const long long e = (long long)b * L + pos;
                    src[2 * e]     = kp0[2 * i];
                    src[2 * e + 1] = kp0[2 * i + 1];
                    tgt[2 * e]     = kp1[2 * i];
                    tgt[2 * e + 1] = kp1[2 * i + 1];
                    sco[e]         = conf[i];
                }
            }
        }
    }
}

extern "C" void kernel_launch(void* const* d_in, const int* in_sizes, int n_in,
                              void* d_out, int out_size, void* d_ws, size_t ws_size,
                              hipStream_t stream) {
    const float* kp0  = (const float*)d_in[0];
    const float* kp1  = (const float*)d_in[1];
    const float* conf = (const float*)d_in[2];
    const int* bidx   = (const int*)d_in[3];
    const int* nb_p   = (const int*)d_in[4];   // num_batches (scalar on device)
    const int* mp_p   = (const int*)d_in[5];   // max_points  (scalar on device)

    const int n = in_sizes[2];                 // total points
    const long long M = (long long)out_size / 5;  // num_batches * max_points

    int* starts = (int*)d_ws;                  // MAX_B ints

    loftr_compute_starts<<<(MAX_B + 255) / 256, 256, 0, stream>>>(bidx, n, nb_p, starts);

    const int block = 256;
    const long long nq = ((long long)n + 3) >> 2;
    long long blocks_needed = (nq + block - 1) / block;
    int grid = (int)((blocks_needed < 2048) ? blocks_needed : 2048);
    if (grid < 1) grid = 1;
    loftr_scatter<<<grid, block, 0, stream>>>(kp0, kp1, conf, starts, nb_p, mp_p,
                                              (float*)d_out, n, M);
}

// Round 2
// 139.470 us; speedup vs baseline: 1.0762x; 1.0762x over previous
//
#include <hip/hip_runtime.h>

// LoFTR2Tensor: jagged -> padded dense scatter. For sorted batch_indexes the
// scatter is piecewise-contiguous: a 2048-point chunk lies entirely in one
// batch unless it straddles a batch boundary (rare). So each block does ONE
// wave-uniform binary search over batch_indexes, then a pure unrolled float4
// copy of its three stream slices (kp0, kp1, conf). Boundary/tail/misaligned
// chunks fall back to a per-point scalar path (mode="drop" semantics kept).

#define CHUNK 2048   // points per block
#define BLOCK 256

__global__ __launch_bounds__(BLOCK)
void loftr_copy(const float* __restrict__ kp0,
                const float* __restrict__ kp1,
                const float* __restrict__ conf,
                const int* __restrict__ bidx,
                const int* __restrict__ mp_p,
                float* __restrict__ out,
                int n, long long M /* = num_batches*max_points */) {
    __shared__ long long s_base;
    __shared__ int s_fast;

    const int L = *mp_p;
    const long long i0 = (long long)blockIdx.x * CHUNK;
    if (i0 >= (long long)n) return;
    const long long iend = i0 + CHUNK;   // exclusive

    if (threadIdx.x == 0) {
        int fast = 0;
        long long base = 0;
        const int b0 = bidx[i0];
        if (iend <= (long long)n && bidx[iend - 1] == b0) {
            // lower_bound of b0 in bidx[0, i0]: first occurrence of batch b0
            long long lo = 0, hi = i0;
            while (lo < hi) {
                long long mid = (lo + hi) >> 1;
                if (bidx[mid] < b0) lo = mid + 1; else hi = mid;
            }
            const long long pos0 = i0 - lo;
            base = (long long)b0 * L + pos0;
            if (pos0 + CHUNK <= (long long)L && (base & 3LL) == 0LL) fast = 1;
        }
        s_base = base;
        s_fast = fast;
    }
    __syncthreads();

    float* __restrict__ src = out;            // (B, L, 2)
    float* __restrict__ tgt = out + 2 * M;    // (B, L, 2)
    float* __restrict__ sco = out + 4 * M;    // (B, L)

    if (s_fast) {
        // Whole chunk in one batch, contiguous and 16B-aligned both sides.
        const long long base = s_base;
        const float4* __restrict__ a4 = reinterpret_cast<const float4*>(kp0 + 2 * i0);
        const float4* __restrict__ b4 = reinterpret_cast<const float4*>(kp1 + 2 * i0);
        const float4* __restrict__ c4 = reinterpret_cast<const float4*>(conf + i0);
        float4* __restrict__ s4 = reinterpret_cast<float4*>(src + 2 * base);
        float4* __restrict__ t4 = reinterpret_cast<float4*>(tgt + 2 * base);
        float4* __restrict__ o4 = reinterpret_cast<float4*>(sco + base);
        const int t = threadIdx.x;

        // kp streams: 2*CHUNK/4 = 1024 float4 each -> 4 per thread.
        // conf stream: CHUNK/4 = 512 float4 -> 2 per thread.
        // All loads independent -> full MLP; perfectly coalesced (1KB/wave/instr).
        float4 ra0 = a4[t];         float4 rb0 = b4[t];
        float4 ra1 = a4[t + 256];   float4 rb1 = b4[t + 256];
        float4 ra2 = a4[t + 512];   float4 rb2 = b4[t + 512];
        float4 ra3 = a4[t + 768];   float4 rb3 = b4[t + 768];
        float4 rc0 = c4[t];         float4 rc1 = c4[t + 256];

        s4[t]       = ra0;  s4[t + 256] = ra1;
        s4[t + 512] = ra2;  s4[t + 768] = ra3;
        t4[t]       = rb0;  t4[t + 256] = rb1;
        t4[t + 512] = rb2;  t4[t + 768] = rb3;
        o4[t]       = rc0;  o4[t + 256] = rc1;
    } else {
        // General sorted-jagged fallback: per-point search (boundary/tail only).
        for (long long i = i0 + threadIdx.x; i < iend && i < (long long)n; i += BLOCK) {
            const int b = bidx[i];
            long long lo = 0, hi = i;
            while (lo < hi) {
                long long mid = (lo + hi) >> 1;
                if (bidx[mid] < b) lo = mid + 1; else hi = mid;
            }
            const long long pos = i - lo;
            if (pos < (long long)L) {   // mode="drop"
                const long long e = (long long)b * L + pos;
                src[2 * e]     = kp0[2 * i];
                src[2 * e + 1] = kp0[2 * i + 1];
                tgt[2 * e]     = kp1[2 * i];
                tgt[2 * e + 1] = kp1[2 * i + 1];
                sco[e]         = conf[i];
            }
        }
    }
}

extern "C" void kernel_launch(void* const* d_in, const int* in_sizes, int n_in,
                              void* d_out, int out_size, void* d_ws, size_t ws_size,
                              hipStream_t stream) {
    const float* kp0  = (const float*)d_in[0];
    const float* kp1  = (const float*)d_in[1];
    const float* conf = (const float*)d_in[2];
    const int* bidx   = (const int*)d_in[3];
    const int* mp_p   = (const int*)d_in[5];   // max_points (device scalar)

    const int n = in_sizes[2];                 // total points
    const long long M = (long long)out_size / 5;  // num_batches * max_points

    const int grid = (int)(((long long)n + CHUNK - 1) / CHUNK);
    loftr_copy<<<grid, BLOCK, 0, stream>>>(kp0, kp1, conf, bidx, mp_p,
                                           (float*)d_out, n, M);
}

// Round 4
// 115.256 us; speedup vs baseline: 1.3023x; 1.2101x over previous
//
#include <hip/hip_runtime.h>

// LoFTR2Tensor: jagged -> padded dense scatter, sorted batch_indexes.
// Fast path: speculatively guess batch g = i0/L (the equal-count layout) and
// PROVE start[g] == g*L with 4 independent O(1) loads (sorted input =>
// bidx[g*L-1]==g-1 && bidx[g*L]==g  <=>  lower_bound(g)==g*L). This replaces
// the ~24-step dependent binary search (~10k cy/block) with one latency round.
// In the fast path base == i0, so the kernel is a pure identity float4 copy.
// General jagged inputs fall back to a per-point binary search (mode="drop").

#define CHUNK 2048   // points per block
#define BLOCK 256

typedef float vfloat4 __attribute__((ext_vector_type(4)));  // native vector:
// __builtin_nontemporal_* requires a scalar/native-vector pointee (HIP float4
// is a class and is rejected).

__global__ __launch_bounds__(BLOCK)
void loftr_copy(const float* __restrict__ kp0,
                const float* __restrict__ kp1,
                const float* __restrict__ conf,
                const int* __restrict__ bidx,
                const int* __restrict__ mp_p,
                float* __restrict__ out,
                long long n, long long M /* = num_batches*max_points */) {
    const long long i0 = (long long)blockIdx.x * CHUNK;
    if (i0 >= n) return;
    const long long L = *mp_p;               // wave-uniform scalar
    const long long iend = i0 + CHUNK;

    float* __restrict__ src = out;            // (B, L, 2)
    float* __restrict__ tgt = out + 2 * M;    // (B, L, 2)
    float* __restrict__ sco = out + 4 * M;    // (B, L)

    // ---- O(1) fast-path verification (all wave-uniform; no LDS, no barrier)
    bool fast = false;
    if (iend <= n && L > 0) {
        const long long g = i0 / L;
        const long long pos0 = i0 - g * L;
        if (pos0 + CHUNK <= L) {
            const int bi0 = bidx[i0];
            const int bi1 = bidx[iend - 1];
            bool ok = (bi0 == (int)g) && (bi1 == (int)g);
            if (ok && g > 0) {
                ok = (bidx[g * L] == (int)g) && (bidx[g * L - 1] == (int)(g - 1));
            }
            fast = ok;   // proven: start[g] == g*L, whole chunk in batch g
        }
    }

    if (fast) {
        // base = g*L + (i0 - g*L) = i0 -> identity copy, 16B aligned both sides.
        const vfloat4* __restrict__ a4 = reinterpret_cast<const vfloat4*>(kp0 + 2 * i0);
        const vfloat4* __restrict__ b4 = reinterpret_cast<const vfloat4*>(kp1 + 2 * i0);
        const vfloat4* __restrict__ c4 = reinterpret_cast<const vfloat4*>(conf + i0);
        vfloat4* __restrict__ s4 = reinterpret_cast<vfloat4*>(src + 2 * i0);
        vfloat4* __restrict__ t4 = reinterpret_cast<vfloat4*>(tgt + 2 * i0);
        vfloat4* __restrict__ o4 = reinterpret_cast<vfloat4*>(sco + i0);
        const int t = threadIdx.x;

        // kp streams: 2*CHUNK/4 = 1024 float4 each -> 4/thread; conf: 2/thread.
        // All 10 loads independent -> full MLP, perfectly coalesced.
        vfloat4 ra0 = __builtin_nontemporal_load(a4 + t);
        vfloat4 ra1 = __builtin_nontemporal_load(a4 + t + 256);
        vfloat4 ra2 = __builtin_nontemporal_load(a4 + t + 512);
        vfloat4 ra3 = __builtin_nontemporal_load(a4 + t + 768);
        vfloat4 rb0 = __builtin_nontemporal_load(b4 + t);
        vfloat4 rb1 = __builtin_nontemporal_load(b4 + t + 256);
        vfloat4 rb2 = __builtin_nontemporal_load(b4 + t + 512);
        vfloat4 rb3 = __builtin_nontemporal_load(b4 + t + 768);
        vfloat4 rc0 = __builtin_nontemporal_load(c4 + t);
        vfloat4 rc1 = __builtin_nontemporal_load(c4 + t + 256);

        __builtin_nontemporal_store(ra0, s4 + t);
        __builtin_nontemporal_store(ra1, s4 + t + 256);
        __builtin_nontemporal_store(ra2, s4 + t + 512);
        __builtin_nontemporal_store(ra3, s4 + t + 768);
        __builtin_nontemporal_store(rb0, t4 + t);
        __builtin_nontemporal_store(rb1, t4 + t + 256);
        __builtin_nontemporal_store(rb2, t4 + t + 512);
        __builtin_nontemporal_store(rb3, t4 + t + 768);
        __builtin_nontemporal_store(rc0, o4 + t);
        __builtin_nontemporal_store(rc1, o4 + t + 256);
    } else {
        // General sorted-jagged fallback (boundary/tail/non-uniform counts).
        for (long long i = i0 + threadIdx.x; i < iend && i < n; i += BLOCK) {
            const int b = bidx[i];
            long long lo = 0, hi = i;
            while (lo < hi) {
                long long mid = (lo + hi) >> 1;
                if (bidx[mid] < b) lo = mid + 1; else hi = mid;
            }
            const long long pos = i - lo;
            if (pos < L) {   // mode="drop"
                const long long e = (long long)b * L + pos;
                src[2 * e]     = kp0[2 * i];
                src[2 * e + 1] = kp0[2 * i + 1];
                tgt[2 * e]     = kp1[2 * i];
                tgt[2 * e + 1] = kp1[2 * i + 1];
                sco[e]         = conf[i];
            }
        }
    }
}

extern "C" void kernel_launch(void* const* d_in, const int* in_sizes, int n_in,
                              void* d_out, int out_size, void* d_ws, size_t ws_size,
                              hipStream_t stream) {
    const float* kp0  = (const float*)d_in[0];
    const float* kp1  = (const float*)d_in[1];
    const float* conf = (const float*)d_in[2];
    const int* bidx   = (const int*)d_in[3];
    const int* mp_p   = (const int*)d_in[5];   // max_points (device scalar)

    const long long n = in_sizes[2];           // total points
    const long long M = (long long)out_size / 5;  // num_batches * max_points

    const int grid = (int)((n + CHUNK - 1) / CHUNK);
    loftr_copy<<<grid, BLOCK, 0, stream>>>(kp0, kp1, conf, bidx, mp_p,
                                           (float*)d_out, n, M);
}